// Round 9
// baseline (454.108 us; speedup 1.0000x reference)
//
#include <hip/hip_runtime.h>
#include <hip/hip_bf16.h>

typedef unsigned int u32;
typedef unsigned short u16;
typedef unsigned long long u64;
typedef __attribute__((ext_vector_type(8))) short short8;   // 8 bf16 = 4 VGPRs
typedef __attribute__((ext_vector_type(4))) float f32x4;

#define LRELU_SLOPE 0.2f

__device__ inline float bfbits(u32 hi) { union { u32 i; float f; } v; v.i = hi; return v.f; }
__device__ inline float bflo(u32 w) { return bfbits(w << 16); }
__device__ inline float bfhi(u32 w) { return bfbits(w & 0xFFFF0000u); }
__device__ inline float bf2f(u16 s) { return bfbits(((u32)s) << 16); }
__device__ inline u16 f2bf(float f) {
  union { float f; u32 i; } v; v.f = f;
  u32 r = v.i + 0x7FFFu + ((v.i >> 16) & 1u); // round-to-nearest-even
  return (u16)(r >> 16);
}

// ------------------------------------------------ dtype sniff: bf16-packed vs f32
__global__ void detect_kernel(const u32* __restrict__ g, int nwords, int* __restrict__ mode) {
  __shared__ int cnt;
  if (threadIdx.x == 0) cnt = 0;
  __syncthreads();
  int c = 0;
  for (int i = threadIdx.x; i < nwords; i += blockDim.x) {
    u32 e = g[i] & 0x7F80u;
    if (e >= 0x3000u && e <= 0x4180u) c++;
  }
  atomicAdd(&cnt, c);
  __syncthreads();
  if (threadIdx.x == 0) *mode = (2 * cnt > nwords) ? 1 : 0; // 1 = inputs are bf16
}

// ------------------------------------------------ input normalization
// bf16 mode: layer-0 proj reads g directly; this kernel early-outs (no copy).
__global__ void conv_x_kernel(const void* __restrict__ g, u16* __restrict__ x, int n,
                              const int* __restrict__ mode) {
  if (*mode) return;
  int i = blockIdx.x * blockDim.x + threadIdx.x;
  if (i >= n) return;
  x[i] = f2bf(((const float*)g)[i]);
}

// params -> pf (f32) then wfrag (MFMA B-frag order), single block.
// pf: [0,4096) W row-major, [4096,4160) att_src, [4160,4224) att_dst, [4224,4288) bias
__global__ void params_kernel(const void* __restrict__ W, const void* __restrict__ as,
                              const void* __restrict__ ad, const void* __restrict__ bs,
                              float* __restrict__ pf, u16* __restrict__ wfrag,
                              const int* __restrict__ mode) {
  int md = *mode;
  for (int i = threadIdx.x; i < 4288; i += 256) {
    const void* p; int j;
    if (i < 4096)      { p = W;  j = i; }
    else if (i < 4160) { p = as; j = i - 4096; }
    else if (i < 4224) { p = ad; j = i - 4160; }
    else               { p = bs; j = i - 4224; }
    pf[i] = md ? bf2f(((const u16*)p)[j]) : ((const float*)p)[j];
  }
  __syncthreads();
  for (int i = threadIdx.x; i < 4096; i += 256) {
    int f = i >> 9, lane = (i >> 3) & 63, j = i & 7;
    int c = f >> 1, t = f & 1;
    int k = 32 * t + 8 * (lane >> 4) + j;
    int n = 16 * c + (lane & 15);
    wfrag[i] = f2bf(pf[k * 64 + n]);
  }
}

// ------------------------------------------------ CSR build, 3-phase XCD-local
// Phase A: compact (src,dst) into 8 per-XCD-range regions (one edge-list read,
// LDS-aggregated bases, compacted writes).
__global__ void __launch_bounds__(256) binA_kernel(
    const int* __restrict__ src, const int* __restrict__ dst, int* __restrict__ gcnt,
    uint2* __restrict__ binned, int E, int nper, int cap) {
  __shared__ int lcnt[8], lbase[8], lcur[8];
  const int K = 8;
  int tile0 = blockIdx.x * (256 * K);
  int t = threadIdx.x;
  if (t < 8) { lcnt[t] = 0; lcur[t] = 0; }
  __syncthreads();
  int dv[K], sv[K], bv[K];
#pragma unroll
  for (int j = 0; j < K; ++j) {
    int idx = tile0 + j * 256 + t;
    bool ok = idx < E;
    int d = ok ? __builtin_nontemporal_load(&dst[idx]) : 0;
    int s = ok ? __builtin_nontemporal_load(&src[idx]) : 0;
    int b = -1;
    if (ok) {
      b = (d >= 4 * nper) ? 4 : 0;
      if (d >= (b + 2) * nper) b += 2;
      if (d >= (b + 1) * nper) b += 1;
      atomicAdd(&lcnt[b], 1);
    }
    dv[j] = d; sv[j] = s; bv[j] = b;
  }
  __syncthreads();
  if (t < 8) lbase[t] = atomicAdd(&gcnt[t], lcnt[t]);
  __syncthreads();
#pragma unroll
  for (int j = 0; j < K; ++j) {
    int b = bv[j];
    if (b >= 0) {
      int slot = lbase[b] + atomicAdd(&lcur[b], 1);
      if (slot < cap) binned[(size_t)b * cap + slot] = make_uint2((u32)sv[j], (u32)dv[j]);
    }
  }
}

// Phase B1: per-XCD histogram over its own region (deg lines L2-local, hot).
__global__ void hist_local_kernel(const uint2* __restrict__ binned, const int* __restrict__ gcnt,
                                  int* __restrict__ deg, int cap) {
  int b = blockIdx.x & 7;
  int vb = blockIdx.x >> 3, nvb = gridDim.x >> 3;
  int cnt = gcnt[b]; if (cnt > cap) cnt = cap;
  const uint2* reg = binned + (size_t)b * cap;
  for (int i = vb * blockDim.x + threadIdx.x; i < cnt; i += nvb * blockDim.x)
    atomicAdd(&deg[reg[i].y], 1);
}

// Phase B2: per-XCD scatter into packed CSR (cursor + csr segment L2-local).
__global__ void scatter_local_kernel(const uint2* __restrict__ binned, const int* __restrict__ gcnt,
                                     int* __restrict__ cursor, int* __restrict__ csr_src, int cap) {
  int b = blockIdx.x & 7;
  int vb = blockIdx.x >> 3, nvb = gridDim.x >> 3;
  int cnt = gcnt[b]; if (cnt > cap) cnt = cap;
  const uint2* reg = binned + (size_t)b * cap;
  for (int i = vb * blockDim.x + threadIdx.x; i < cnt; i += nvb * blockDim.x) {
    uint2 r = reg[i];
    int p = atomicAdd(&cursor[r.y], 1);
    csr_src[p] = (int)r.x;
  }
}

__global__ void scan1_kernel(const int* __restrict__ deg, int* __restrict__ row_off,
                             int* __restrict__ partials, int N) {
  __shared__ int smem[1024];
  int t = threadIdx.x;
  int idx = blockIdx.x * 1024 + t;
  int v = (idx < N) ? deg[idx] : 0;
  smem[t] = v;
  __syncthreads();
  for (int off = 1; off < 1024; off <<= 1) {
    int u = (t >= off) ? smem[t - off] : 0;
    __syncthreads();
    smem[t] += u;
    __syncthreads();
  }
  if (idx < N) row_off[idx + 1] = smem[t];
  if (t == 1023) partials[blockIdx.x] = smem[t];
}

__global__ void scan2_kernel(int* __restrict__ partials, int P) {
  __shared__ int smem[1024];
  int t = threadIdx.x;
  int v = (t < P) ? partials[t] : 0;
  smem[t] = v;
  __syncthreads();
  for (int off = 1; off < 1024; off <<= 1) {
    int u = (t >= off) ? smem[t - off] : 0;
    __syncthreads();
    smem[t] += u;
    __syncthreads();
  }
  if (t < P) partials[t] = smem[t];
}

__global__ void scan3_kernel(int* __restrict__ row_off, const int* __restrict__ partials, int N) {
  int b = blockIdx.x;
  int idx = b * 1024 + threadIdx.x;
  if (b > 0 && idx < N) row_off[idx + 1] += partials[b - 1];
  if (idx == 0) row_off[0] = 0;
}

// ------------------------------------------------ h = x@W via MFMA, fused a_src/a_dst
__global__ void __launch_bounds__(256) proj_mfma_kernel(
    const u16* __restrict__ x, const void* __restrict__ graw, const int* __restrict__ mode,
    int first, const u16* __restrict__ wfrag, const float* __restrict__ pf,
    u16* __restrict__ h, float* __restrict__ a_src, float* __restrict__ a_dst, int N) {
  int lane = threadIdx.x & 63;
  int quad = lane >> 4, m = lane & 15;
  int wtile = (int)((blockIdx.x * (size_t)blockDim.x + threadIdx.x) >> 6);
  int ntiles = (N + 15) >> 4;
  int nwaves = (int)((gridDim.x * (size_t)blockDim.x) >> 6);

  const u16* xin = (first && *mode) ? (const u16*)graw : x;

  short8 bfrag[8];
#pragma unroll
  for (int f = 0; f < 8; ++f)
    bfrag[f] = *(const short8*)(wfrag + f * 512 + lane * 8);
  float asv[4], adv[4];
#pragma unroll
  for (int c = 0; c < 4; ++c) {
    asv[c] = pf[4096 + 16 * c + m];
    adv[c] = pf[4160 + 16 * c + m];
  }

  for (int tile = wtile; tile < ntiles; tile += nwaves) {
    int row0 = tile << 4;
    int rl = row0 + m; if (rl > N - 1) rl = N - 1;
    const u16* xr = xin + (size_t)rl * 64 + 8 * quad;
    short8 a0 = *(const short8*)(xr);
    short8 a1 = *(const short8*)(xr + 32);

    f32x4 acc[4];
#pragma unroll
    for (int c = 0; c < 4; ++c) {
      f32x4 z = {0.f, 0.f, 0.f, 0.f};
      z = __builtin_amdgcn_mfma_f32_16x16x32_bf16(a0, bfrag[2 * c + 0], z, 0, 0, 0);
      z = __builtin_amdgcn_mfma_f32_16x16x32_bf16(a1, bfrag[2 * c + 1], z, 0, 0, 0);
      acc[c] = z;
    }

#pragma unroll
    for (int r = 0; r < 4; ++r) {
      int row = row0 + 4 * quad + r;
      float v0 = acc[0][r], v1 = acc[1][r], v2 = acc[2][r], v3 = acc[3][r];
      if (row < N) {
        u16* hr = h + (size_t)row * 64 + m;
        hr[0]  = f2bf(v0);
        hr[16] = f2bf(v1);
        hr[32] = f2bf(v2);
        hr[48] = f2bf(v3);
      }
      float s1 = v0 * asv[0] + v1 * asv[1] + v2 * asv[2] + v3 * asv[3];
      float s2 = v0 * adv[0] + v1 * adv[1] + v2 * adv[2] + v3 * adv[3];
#pragma unroll
      for (int msk = 1; msk <= 8; msk <<= 1) {
        s1 += __shfl_xor(s1, msk, 64);
        s2 += __shfl_xor(s2, msk, 64);
      }
      if (m == 0 && row < N) { a_src[row] = s1; a_dst[row] = s2; }
    }
  }
}

// ------------------------------------------------ per-dst: softmax + weighted sum + bias
// 4 edge-groups x 16 feature-lanes (4 features each, uint2 loads).
// 2-level butterfly epilogue (10 shuffle-adds vs 27 for 8x8).
__global__ void __launch_bounds__(256) gather_kernel(
    const u16* __restrict__ h, const float* __restrict__ a_src,
    const float* __restrict__ a_dst, const int* __restrict__ row_off,
    const int* __restrict__ csr_src, const float* __restrict__ pf,
    u16* __restrict__ xout, void* __restrict__ dout, int N, int last,
    const int* __restrict__ mode) {
  int lane = threadIdx.x & 63;
  int eg = lane >> 4;   // edge group 0..3
  int fg = lane & 15;   // feature quartet 0..15
  int i = (int)((blockIdx.x * blockDim.x + threadIdx.x) >> 6);
  if (i >= N) return;   // wave-uniform exit

  int beg = row_off[i], end = row_off[i + 1];
  float adv = a_dst[i];
  float acc[4] = {0.f, 0.f, 0.f, 0.f};
  float den = 0.f;

  int e = beg + eg;
  int s_cur = (e < end) ? csr_src[e] : -1;
  for (int e0 = beg; e0 < end; e0 += 4) {
    int s = s_cur;
    int e2 = e0 + 4 + eg;
    s_cur = (e2 < end) ? csr_src[e2] : -1;   // prefetch next batch
    if (s >= 0) {
      float t = a_src[s] + adv;
      t = (t > 0.f) ? t : LRELU_SLOPE * t;
      t = fminf(fmaxf(t, -60.f), 60.f);
      float w = __expf(t);
      den += w;
      uint2 hv = ((const uint2*)(h + (size_t)s * 64))[fg];
      acc[0] += w * bflo(hv.x); acc[1] += w * bfhi(hv.x);
      acc[2] += w * bflo(hv.y); acc[3] += w * bfhi(hv.y);
    }
  }

#pragma unroll
  for (int msk = 16; msk <= 32; msk <<= 1) {
    den += __shfl_xor(den, msk, 64);
#pragma unroll
    for (int j = 0; j < 4; ++j) acc[j] += __shfl_xor(acc[j], msk, 64);
  }
  float inv = (den > 0.f) ? 1.f / den : 0.f;

  if (*mode || !last) {
    if (eg == 0) {   // 16 lanes x uint2 = 128B coalesced row
      float f0 = acc[0] * inv + pf[4224 + 4 * fg + 0];
      float f1 = acc[1] * inv + pf[4224 + 4 * fg + 1];
      float f2 = acc[2] * inv + pf[4224 + 4 * fg + 2];
      float f3 = acc[3] * inv + pf[4224 + 4 * fg + 3];
      u32 o0 = (u32)f2bf(f0) | ((u32)f2bf(f1) << 16);
      u32 o1 = (u32)f2bf(f2) | ((u32)f2bf(f3) << 16);
      u16* base = last ? (u16*)dout : xout;
      *(uint2*)(base + (size_t)i * 64 + fg * 4) = make_uint2(o0, o1);
    }
  } else {
    float o[4];
#pragma unroll
    for (int j = 0; j < 4; ++j)
      o[j] = acc[j] * inv + pf[4224 + 4 * fg + j];
    int srcl = (lane >> 2) & 15;  // eg==0 lane holding this feature quartet
    float t0 = 0.f;
#pragma unroll
    for (int j = 0; j < 4; ++j) {
      float v = __shfl(o[j], srcl, 64);
      t0 = ((lane & 3) == j) ? v : t0;
    }
    ((float*)dout)[(size_t)i * 64 + lane] = t0;
  }
}

// ------------------------------------------------ launcher
extern "C" void kernel_launch(void* const* d_in, const int* in_sizes, int n_in,
                              void* d_out, int out_size, void* d_ws, size_t ws_size,
                              hipStream_t stream) {
  const void* g     = d_in[0];
  const int*  edge  = (const int*)d_in[1];
  const void* Wp    = d_in[2];
  const void* attsp = d_in[3];
  const void* attdp = d_in[4];
  const void* biasp = d_in[5];

  const int D = 64;
  const int N = in_sizes[0] / D;
  const int E = in_sizes[1] / 2;
  const int* src = edge;
  const int* dst = edge + E;

  char* ws = (char*)d_ws;
  size_t off = 0;
  auto alloc = [&](size_t bytes) -> char* {
    char* p = ws + off;
    off += (bytes + 255) & ~size_t(255);
    return p;
  };
  u16*   x        = (u16*)alloc((size_t)N * D * sizeof(u16));    // 12.8 MB
  u16*   h        = (u16*)alloc((size_t)N * D * sizeof(u16));    // 12.8 MB
  float* pf       = (float*)alloc(4288 * sizeof(float));
  u16*   wfrag    = (u16*)alloc(4096 * sizeof(u16));
  float* a_src    = (float*)alloc((size_t)N * sizeof(float));
  float* a_dst    = (float*)alloc((size_t)N * sizeof(float));
  int*   deg      = (int*)alloc((size_t)N * sizeof(int));
  int*   row_off  = (int*)alloc((size_t)(N + 1) * sizeof(int));
  int*   cursor   = (int*)alloc((size_t)N * sizeof(int));
  int*   csr_src  = (int*)alloc((size_t)E * sizeof(int));        // 4 MB
  int*   partials = (int*)alloc(1024 * sizeof(int));
  int*   mode     = (int*)alloc(256);
  int*   gcnt     = (int*)alloc(256);
  int    cap      = E / 8 + 16384;                               // per-XCD region capacity
  uint2* binned   = (uint2*)alloc((size_t)8 * cap * sizeof(uint2)); // ~9 MB

  detect_kernel<<<1, 256, 0, stream>>>((const u32*)g, 4096, mode);

  int n64 = N * D;
  conv_x_kernel<<<(n64 + 255) / 256, 256, 0, stream>>>(g, x, n64, mode);
  params_kernel<<<1, 256, 0, stream>>>(Wp, attsp, attdp, biasp, pf, wfrag, mode);

  int nper = (N + 7) / 8;  // dst ids per XCD bucket
  hipMemsetAsync(deg, 0, (size_t)N * sizeof(int), stream);
  hipMemsetAsync(gcnt, 0, 8 * sizeof(int), stream);
  int abl = (E + 2047) / 2048;  // 8 edges/thread, 256 threads
  binA_kernel<<<abl, 256, 0, stream>>>(src, dst, gcnt, binned, E, nper, cap);
  hist_local_kernel<<<1024, 256, 0, stream>>>(binned, gcnt, deg, cap);
  int nblk = (N + 1023) / 1024;
  scan1_kernel<<<nblk, 1024, 0, stream>>>(deg, row_off, partials, N);
  scan2_kernel<<<1, 1024, 0, stream>>>(partials, nblk);
  scan3_kernel<<<nblk, 1024, 0, stream>>>(row_off, partials, N);
  hipMemcpyAsync(cursor, row_off, (size_t)N * sizeof(int), hipMemcpyDeviceToDevice, stream);
  scatter_local_kernel<<<1024, 256, 0, stream>>>(binned, gcnt, cursor, csr_src, cap);

  int ntiles = (N + 15) / 16;
  int tblocks = (ntiles + 3) / 4;  // 1 tile/wave
  for (int layer = 0; layer < 4; ++layer) {
    proj_mfma_kernel<<<tblocks, 256, 0, stream>>>(x, g, mode, layer == 0 ? 1 : 0,
                                                  wfrag, pf, h, a_src, a_dst, N);
    int last = (layer == 3) ? 1 : 0;
    gather_kernel<<<(N + 3) / 4, 256, 0, stream>>>(h, a_src, a_dst, row_off, csr_src, pf,
                                                   x, d_out, N, last, mode);
  }
}

// Round 10
// 418.849 us; speedup vs baseline: 1.0842x; 1.0842x over previous
//
#include <hip/hip_runtime.h>
#include <hip/hip_bf16.h>

typedef unsigned int u32;
typedef unsigned short u16;
typedef unsigned long long u64;
typedef __attribute__((ext_vector_type(8))) short short8;   // 8 bf16 = 4 VGPRs
typedef __attribute__((ext_vector_type(4))) float f32x4;

#define LRELU_SLOPE 0.2f

__device__ inline float bfbits(u32 hi) { union { u32 i; float f; } v; v.i = hi; return v.f; }
__device__ inline float bflo(u32 w) { return bfbits(w << 16); }
__device__ inline float bfhi(u32 w) { return bfbits(w & 0xFFFF0000u); }
__device__ inline float bf2f(u16 s) { return bfbits(((u32)s) << 16); }
__device__ inline u16 f2bf(float f) {
  union { float f; u32 i; } v; v.f = f;
  u32 r = v.i + 0x7FFFu + ((v.i >> 16) & 1u); // round-to-nearest-even
  return (u16)(r >> 16);
}

// ------------------------------------------------ dtype sniff: bf16-packed vs f32
__global__ void detect_kernel(const u32* __restrict__ g, int nwords, int* __restrict__ mode) {
  __shared__ int cnt;
  if (threadIdx.x == 0) cnt = 0;
  __syncthreads();
  int c = 0;
  for (int i = threadIdx.x; i < nwords; i += blockDim.x) {
    u32 e = g[i] & 0x7F80u;
    if (e >= 0x3000u && e <= 0x4180u) c++;
  }
  atomicAdd(&cnt, c);
  __syncthreads();
  if (threadIdx.x == 0) *mode = (2 * cnt > nwords) ? 1 : 0; // 1 = inputs are bf16
}

// ------------------------------------------------ input normalization
// bf16 mode: layer-0 proj reads g directly; this kernel early-outs (no copy).
__global__ void conv_x_kernel(const void* __restrict__ g, u16* __restrict__ x, int n,
                              const int* __restrict__ mode) {
  if (*mode) return;
  int i = blockIdx.x * blockDim.x + threadIdx.x;
  if (i >= n) return;
  x[i] = f2bf(((const float*)g)[i]);
}

// params -> pf (f32) then wfrag (MFMA B-frag order), single block.
// pf: [0,4096) W row-major, [4096,4160) att_src, [4160,4224) att_dst, [4224,4288) bias
__global__ void params_kernel(const void* __restrict__ W, const void* __restrict__ as,
                              const void* __restrict__ ad, const void* __restrict__ bs,
                              float* __restrict__ pf, u16* __restrict__ wfrag,
                              const int* __restrict__ mode) {
  int md = *mode;
  for (int i = threadIdx.x; i < 4288; i += 256) {
    const void* p; int j;
    if (i < 4096)      { p = W;  j = i; }
    else if (i < 4160) { p = as; j = i - 4096; }
    else if (i < 4224) { p = ad; j = i - 4160; }
    else               { p = bs; j = i - 4224; }
    pf[i] = md ? bf2f(((const u16*)p)[j]) : ((const float*)p)[j];
  }
  __syncthreads();
  for (int i = threadIdx.x; i < 4096; i += 256) {
    int f = i >> 9, lane = (i >> 3) & 63, j = i & 7;
    int c = f >> 1, t = f & 1;
    int k = 32 * t + 8 * (lane >> 4) + j;
    int n = 16 * c + (lane & 15);
    wfrag[i] = f2bf(pf[k * 64 + n]);
  }
}

// ------------------------------------------------ CSR build, 3-phase XCD-local
__global__ void __launch_bounds__(256) binA_kernel(
    const int* __restrict__ src, const int* __restrict__ dst, int* __restrict__ gcnt,
    uint2* __restrict__ binned, int E, int nper, int cap) {
  __shared__ int lcnt[8], lbase[8], lcur[8];
  const int K = 8;
  int tile0 = blockIdx.x * (256 * K);
  int t = threadIdx.x;
  if (t < 8) { lcnt[t] = 0; lcur[t] = 0; }
  __syncthreads();
  int dv[K], sv[K], bv[K];
#pragma unroll
  for (int j = 0; j < K; ++j) {
    int idx = tile0 + j * 256 + t;
    bool ok = idx < E;
    int d = ok ? __builtin_nontemporal_load(&dst[idx]) : 0;
    int s = ok ? __builtin_nontemporal_load(&src[idx]) : 0;
    int b = -1;
    if (ok) {
      b = (d >= 4 * nper) ? 4 : 0;
      if (d >= (b + 2) * nper) b += 2;
      if (d >= (b + 1) * nper) b += 1;
      atomicAdd(&lcnt[b], 1);
    }
    dv[j] = d; sv[j] = s; bv[j] = b;
  }
  __syncthreads();
  if (t < 8) lbase[t] = atomicAdd(&gcnt[t], lcnt[t]);
  __syncthreads();
#pragma unroll
  for (int j = 0; j < K; ++j) {
    int b = bv[j];
    if (b >= 0) {
      int slot = lbase[b] + atomicAdd(&lcur[b], 1);
      if (slot < cap) binned[(size_t)b * cap + slot] = make_uint2((u32)sv[j], (u32)dv[j]);
    }
  }
}

__global__ void hist_local_kernel(const uint2* __restrict__ binned, const int* __restrict__ gcnt,
                                  int* __restrict__ deg, int cap) {
  int b = blockIdx.x & 7;
  int vb = blockIdx.x >> 3, nvb = gridDim.x >> 3;
  int cnt = gcnt[b]; if (cnt > cap) cnt = cap;
  const uint2* reg = binned + (size_t)b * cap;
  for (int i = vb * blockDim.x + threadIdx.x; i < cnt; i += nvb * blockDim.x)
    atomicAdd(&deg[reg[i].y], 1);
}

__global__ void scatter_local_kernel(const uint2* __restrict__ binned, const int* __restrict__ gcnt,
                                     int* __restrict__ cursor, int* __restrict__ csr_src, int cap) {
  int b = blockIdx.x & 7;
  int vb = blockIdx.x >> 3, nvb = gridDim.x >> 3;
  int cnt = gcnt[b]; if (cnt > cap) cnt = cap;
  const uint2* reg = binned + (size_t)b * cap;
  for (int i = vb * blockDim.x + threadIdx.x; i < cnt; i += nvb * blockDim.x) {
    uint2 r = reg[i];
    int p = atomicAdd(&cursor[r.y], 1);
    csr_src[p] = (int)r.x;
  }
}

__global__ void scan1_kernel(const int* __restrict__ deg, int* __restrict__ row_off,
                             int* __restrict__ partials, int N) {
  __shared__ int smem[1024];
  int t = threadIdx.x;
  int idx = blockIdx.x * 1024 + t;
  int v = (idx < N) ? deg[idx] : 0;
  smem[t] = v;
  __syncthreads();
  for (int off = 1; off < 1024; off <<= 1) {
    int u = (t >= off) ? smem[t - off] : 0;
    __syncthreads();
    smem[t] += u;
    __syncthreads();
  }
  if (idx < N) row_off[idx + 1] = smem[t];
  if (t == 1023) partials[blockIdx.x] = smem[t];
}

__global__ void scan2_kernel(int* __restrict__ partials, int P) {
  __shared__ int smem[1024];
  int t = threadIdx.x;
  int v = (t < P) ? partials[t] : 0;
  smem[t] = v;
  __syncthreads();
  for (int off = 1; off < 1024; off <<= 1) {
    int u = (t >= off) ? smem[t - off] : 0;
    __syncthreads();
    smem[t] += u;
    __syncthreads();
  }
  if (t < P) partials[t] = smem[t];
}

// finalizes row_off AND initializes cursor (replaces the d2d copy)
__global__ void scan3_kernel(int* __restrict__ row_off, const int* __restrict__ partials,
                             int* __restrict__ cursor, int N) {
  int b = blockIdx.x;
  int idx = b * 1024 + threadIdx.x;
  if (idx < N) {
    int v = row_off[idx + 1] + ((b > 0) ? partials[b - 1] : 0);
    row_off[idx + 1] = v;
    if (idx + 1 < N) cursor[idx + 1] = v;
  }
  if (idx == 0) { row_off[0] = 0; cursor[0] = 0; }
}

// ------------------------------------------------ h = x@W via MFMA, fused a_src/a_dst
__global__ void __launch_bounds__(256) proj_mfma_kernel(
    const u16* __restrict__ x, const void* __restrict__ graw, const int* __restrict__ mode,
    int first, const u16* __restrict__ wfrag, const float* __restrict__ pf,
    u16* __restrict__ h, float* __restrict__ a_src, float* __restrict__ a_dst, int N) {
  int lane = threadIdx.x & 63;
  int quad = lane >> 4, m = lane & 15;
  int wtile = (int)((blockIdx.x * (size_t)blockDim.x + threadIdx.x) >> 6);
  int ntiles = (N + 15) >> 4;
  int nwaves = (int)((gridDim.x * (size_t)blockDim.x) >> 6);

  const u16* xin = (first && *mode) ? (const u16*)graw : x;

  short8 bfrag[8];
#pragma unroll
  for (int f = 0; f < 8; ++f)
    bfrag[f] = *(const short8*)(wfrag + f * 512 + lane * 8);
  float asv[4], adv[4];
#pragma unroll
  for (int c = 0; c < 4; ++c) {
    asv[c] = pf[4096 + 16 * c + m];
    adv[c] = pf[4160 + 16 * c + m];
  }

  for (int tile = wtile; tile < ntiles; tile += nwaves) {
    int row0 = tile << 4;
    int rl = row0 + m; if (rl > N - 1) rl = N - 1;
    const u16* xr = xin + (size_t)rl * 64 + 8 * quad;
    short8 a0 = *(const short8*)(xr);
    short8 a1 = *(const short8*)(xr + 32);

    f32x4 acc[4];
#pragma unroll
    for (int c = 0; c < 4; ++c) {
      f32x4 z = {0.f, 0.f, 0.f, 0.f};
      z = __builtin_amdgcn_mfma_f32_16x16x32_bf16(a0, bfrag[2 * c + 0], z, 0, 0, 0);
      z = __builtin_amdgcn_mfma_f32_16x16x32_bf16(a1, bfrag[2 * c + 1], z, 0, 0, 0);
      acc[c] = z;
    }

#pragma unroll
    for (int r = 0; r < 4; ++r) {
      int row = row0 + 4 * quad + r;
      float v0 = acc[0][r], v1 = acc[1][r], v2 = acc[2][r], v3 = acc[3][r];
      if (row < N) {
        u16* hr = h + (size_t)row * 64 + m;
        hr[0]  = f2bf(v0);
        hr[16] = f2bf(v1);
        hr[32] = f2bf(v2);
        hr[48] = f2bf(v3);
      }
      float s1 = v0 * asv[0] + v1 * asv[1] + v2 * asv[2] + v3 * asv[3];
      float s2 = v0 * adv[0] + v1 * adv[1] + v2 * adv[2] + v3 * adv[3];
#pragma unroll
      for (int msk = 1; msk <= 8; msk <<= 1) {
        s1 += __shfl_xor(s1, msk, 64);
        s2 += __shfl_xor(s2, msk, 64);
      }
      if (m == 0 && row < N) { a_src[row] = s1; a_dst[row] = s2; }
    }
  }
}

// ------------------------------------------------ per-dst: softmax + weighted sum + bias
// 8 edge-groups x 8 feature-lanes, DUAL-batch chunks of 16: both csr loads
// issue together, then all four a/h loads together -> 2 serial latencies per
// 16 edges instead of 4 (the s->a/h chain was the measured stall).
__global__ void __launch_bounds__(256) gather_kernel(
    const u16* __restrict__ h, const float* __restrict__ a_src,
    const float* __restrict__ a_dst, const int* __restrict__ row_off,
    const int* __restrict__ csr_src, const float* __restrict__ pf,
    u16* __restrict__ xout, void* __restrict__ dout, int N, int last,
    const int* __restrict__ mode) {
  int lane = threadIdx.x & 63;
  int eg = lane >> 3;   // edge group 0..7
  int fg = lane & 7;    // feature octet 0..7
  int i = (int)((blockIdx.x * blockDim.x + threadIdx.x) >> 6);
  if (i >= N) return;   // wave-uniform exit

  int beg = row_off[i], end = row_off[i + 1];
  float adv = a_dst[i];
  float acc[8] = {0.f, 0.f, 0.f, 0.f, 0.f, 0.f, 0.f, 0.f};
  float den = 0.f;

  if (beg < end) {
    int lastE = end - 1;
    for (int b0 = beg; b0 < end; b0 += 16) {
      int eA = b0 + eg;
      int eB = b0 + 8 + eg;
      float vA = (eA < end) ? 1.f : 0.f;
      float vB = (eB < end) ? 1.f : 0.f;
      int sA = csr_src[(eA < end) ? eA : lastE];   // independent, issue together
      int sB = csr_src[(eB < end) ? eB : lastE];
      float aA = a_src[sA];                        // 4 loads issue together
      float aB = a_src[sB];
      uint4 hA = ((const uint4*)(h + (size_t)sA * 64))[fg];
      uint4 hB = ((const uint4*)(h + (size_t)sB * 64))[fg];

      float tA = aA + adv;
      tA = (tA > 0.f) ? tA : LRELU_SLOPE * tA;
      float wA = __expf(fminf(tA, 60.f)) * vA;
      float tB = aB + adv;
      tB = (tB > 0.f) ? tB : LRELU_SLOPE * tB;
      float wB = __expf(fminf(tB, 60.f)) * vB;
      den += wA + wB;
      acc[0] += wA * bflo(hA.x) + wB * bflo(hB.x);
      acc[1] += wA * bfhi(hA.x) + wB * bfhi(hB.x);
      acc[2] += wA * bflo(hA.y) + wB * bflo(hB.y);
      acc[3] += wA * bfhi(hA.y) + wB * bfhi(hB.y);
      acc[4] += wA * bflo(hA.z) + wB * bflo(hB.z);
      acc[5] += wA * bfhi(hA.z) + wB * bfhi(hB.z);
      acc[6] += wA * bflo(hA.w) + wB * bflo(hB.w);
      acc[7] += wA * bfhi(hA.w) + wB * bfhi(hB.w);
    }
  }

#pragma unroll
  for (int msk = 8; msk <= 32; msk <<= 1) {
    den += __shfl_xor(den, msk, 64);
#pragma unroll
    for (int j = 0; j < 8; ++j) acc[j] += __shfl_xor(acc[j], msk, 64);
  }
  float inv = (den > 0.f) ? 1.f / den : 0.f;

  if (*mode || !last) {
    if (eg == 0) {
      u32 o[4];
#pragma unroll
      for (int j = 0; j < 4; ++j) {
        float f0 = acc[2 * j]     * inv + pf[4224 + 8 * fg + 2 * j];
        float f1 = acc[2 * j + 1] * inv + pf[4224 + 8 * fg + 2 * j + 1];
        o[j] = (u32)f2bf(f0) | ((u32)f2bf(f1) << 16);
      }
      u16* base = last ? (u16*)dout : xout;
      *(uint4*)(base + (size_t)i * 64 + fg * 8) = make_uint4(o[0], o[1], o[2], o[3]);
    }
  } else {
    float o[8];
#pragma unroll
    for (int j = 0; j < 8; ++j)
      o[j] = acc[j] * inv + pf[4224 + 8 * fg + j];
    int srcl = lane >> 3;
    float t0 = 0.f;
#pragma unroll
    for (int j = 0; j < 8; ++j) {
      float v = __shfl(o[j], srcl, 64);
      t0 = ((lane & 7) == j) ? v : t0;
    }
    ((float*)dout)[(size_t)i * 64 + lane] = t0;
  }
}

// ------------------------------------------------ launcher
extern "C" void kernel_launch(void* const* d_in, const int* in_sizes, int n_in,
                              void* d_out, int out_size, void* d_ws, size_t ws_size,
                              hipStream_t stream) {
  const void* g     = d_in[0];
  const int*  edge  = (const int*)d_in[1];
  const void* Wp    = d_in[2];
  const void* attsp = d_in[3];
  const void* attdp = d_in[4];
  const void* biasp = d_in[5];

  const int D = 64;
  const int N = in_sizes[0] / D;
  const int E = in_sizes[1] / 2;
  const int* src = edge;
  const int* dst = edge + E;

  char* ws = (char*)d_ws;
  size_t off = 0;
  auto alloc = [&](size_t bytes) -> char* {
    char* p = ws + off;
    off += (bytes + 255) & ~size_t(255);
    return p;
  };
  u16*   x        = (u16*)alloc((size_t)N * D * sizeof(u16));    // 12.8 MB
  u16*   h        = (u16*)alloc((size_t)N * D * sizeof(u16));    // 12.8 MB
  float* pf       = (float*)alloc(4288 * sizeof(float));
  u16*   wfrag    = (u16*)alloc(4096 * sizeof(u16));
  float* a_src    = (float*)alloc((size_t)N * sizeof(float));
  float* a_dst    = (float*)alloc((size_t)N * sizeof(float));
  int*   deg      = (int*)alloc((size_t)N * sizeof(int));
  int*   row_off  = (int*)alloc((size_t)(N + 1) * sizeof(int));
  int*   cursor   = (int*)alloc((size_t)N * sizeof(int));
  int*   csr_src  = (int*)alloc((size_t)E * sizeof(int));        // 4 MB
  int*   partials = (int*)alloc(1024 * sizeof(int));
  int*   mode     = (int*)alloc(256);
  int*   gcnt     = (int*)alloc(256);
  int    cap      = E / 8 + 16384;                               // per-XCD region capacity
  uint2* binned   = (uint2*)alloc((size_t)8 * cap * sizeof(uint2)); // ~9 MB

  detect_kernel<<<1, 256, 0, stream>>>((const u32*)g, 4096, mode);

  int n64 = N * D;
  conv_x_kernel<<<(n64 + 255) / 256, 256, 0, stream>>>(g, x, n64, mode);
  params_kernel<<<1, 256, 0, stream>>>(Wp, attsp, attdp, biasp, pf, wfrag, mode);

  int nper = (N + 7) / 8;  // dst ids per XCD bucket
  hipMemsetAsync(deg, 0, (size_t)N * sizeof(int), stream);
  hipMemsetAsync(gcnt, 0, 8 * sizeof(int), stream);
  int abl = (E + 2047) / 2048;  // 8 edges/thread, 256 threads
  binA_kernel<<<abl, 256, 0, stream>>>(src, dst, gcnt, binned, E, nper, cap);
  hist_local_kernel<<<1024, 256, 0, stream>>>(binned, gcnt, deg, cap);
  int nblk = (N + 1023) / 1024;
  scan1_kernel<<<nblk, 1024, 0, stream>>>(deg, row_off, partials, N);
  scan2_kernel<<<1, 1024, 0, stream>>>(partials, nblk);
  scan3_kernel<<<nblk, 1024, 0, stream>>>(row_off, partials, cursor, N);
  scatter_local_kernel<<<1024, 256, 0, stream>>>(binned, gcnt, cursor, csr_src, cap);

  int ntiles = (N + 15) / 16;
  int tblocks = (ntiles + 3) / 4;  // 1 tile/wave
  for (int layer = 0; layer < 4; ++layer) {
    proj_mfma_kernel<<<tblocks, 256, 0, stream>>>(x, g, mode, layer == 0 ? 1 : 0,
                                                  wfrag, pf, h, a_src, a_dst, N);
    int last = (layer == 3) ? 1 : 0;
    gather_kernel<<<(N + 3) / 4, 256, 0, stream>>>(h, a_src, a_dst, row_off, csr_src, pf,
                                                   x, d_out, N, last, mode);
  }
}